// Round 9
// baseline (458.344 us; speedup 1.0000x reference)
//
#include <hip/hip_runtime.h>
#include <hip/hip_bf16.h>

#define M_DIM 64
#define K_DIM 4096
#define N_DIM 14336
#define NBLKS 224       // one block per 64 n-cols
#define KW 1024         // k-range per wave (4 waves cover K=4096)
#define WCHUNKS 32      // 32-k chunks per wave

typedef __attribute__((ext_vector_type(8))) short bf16x8;
typedef __attribute__((ext_vector_type(4))) float f32x4;
typedef unsigned short u16;

// ---------------------------------------------------------------------------
// prep: split x (fp32) into bf16 hi/lo, stored in MFMA-A-fragment layout:
// elem idx = (k/8)*(64*8) + m*8 + (k%8).
__global__ void prep_split(const float* __restrict__ x, u16* __restrict__ xh,
                           u16* __restrict__ xl) {
  int tg = blockIdx.x * blockDim.x + threadIdx.x;  // 0..32767
  int kb = tg & 511;
  int m = tg >> 9;
  const float* xp = x + m * K_DIM + kb * 8;
  u16 hs[8], ls[8];
#pragma unroll
  for (int j = 0; j < 8; ++j) {
    float v = xp[j];
    unsigned hv = __float_as_uint(v) & 0xFFFF0000u;  // bf16 truncate (exact)
    float r = v - __uint_as_float(hv);
    hs[j] = (u16)(hv >> 16);
    ls[j] = (u16)(__float_as_uint(r) >> 16);
  }
  int o = kb * (M_DIM * 8) + m * 8;
  *(uint4*)(xh + o) = *(uint4*)hs;
  *(uint4*)(xl + o) = *(uint4*)ls;
}

__global__ void rowsum_k(const float* __restrict__ x, float* __restrict__ rs) {
  int m = blockIdx.x;
  int t = threadIdx.x;
  float s = 0.f;
  for (int k = t; k < K_DIM; k += 256) s += x[m * K_DIM + k];
#pragma unroll
  for (int off = 32; off > 0; off >>= 1) s += __shfl_down(s, off, 64);
  __shared__ float red[4];
  if ((t & 63) == 0) red[t >> 6] = s;
  __syncthreads();
  if (t == 0) rs[m] = red[0] + red[1] + red[2] + red[3];
}

// ---------------------------------------------------------------------------
// Shared pipeline body for wqmm / wqmm_probe (REPS = K-loop repetitions).
// v5 structure, unchanged from R8 for the real pass.
#define WQMM_BODY(REPS, OUTPTR)                                               \
  __shared__ __align__(16) float red[4][64][66];                              \
  const int t = threadIdx.x;                                                  \
  const int lane = t & 63;                                                    \
  const int wv = t >> 6;                                                      \
  const int quad = lane >> 4;                                                 \
  const int lnk = lane & 15;                                                  \
  const int nbase = blockIdx.x * 64;                                          \
  const int k0 = wv * KW;                                                     \
  int laneoff[4];                                                             \
  _Pragma("unroll") for (int f = 0; f < 4; ++f)                               \
      laneoff[f] = quad * 8 * N_DIM + nbase + lnk + f * 16;                   \
  const u16* xhp = xh + (size_t)(wv * 128 + quad) * 512 + lnk * 8;            \
  const u16* xlp = xl + (size_t)(wv * 128 + quad) * 512 + lnk * 8;            \
  f32x4 acc[4][4] = {};                                                       \
  int raw[2][4][8];                                                           \
  bf16x8 abh[2][4], abl[2][4];                                                \
  for (int rep = 0; rep < (REPS); ++rep) {                                    \
    LOADW(0, 0);                                                              \
    LOADA(0, 0);                                                              \
    for (int c = 0; c < WCHUNKS; c += 2) {                                    \
      LOADW(c + 1, 1);                                                        \
      LOADA(c + 1, 1);                                                        \
      COMPUTE(c, 0);                                                          \
      if (c + 2 < WCHUNKS) {                                                  \
        LOADW(c + 2, 0);                                                      \
        LOADA(c + 2, 0);                                                      \
      }                                                                       \
      COMPUTE(c + 1, 1);                                                      \
    }                                                                         \
  }                                                                           \
  _Pragma("unroll") for (int f = 0; f < 4; ++f)                               \
  _Pragma("unroll") for (int mt = 0; mt < 4; ++mt)                            \
  _Pragma("unroll") for (int r = 0; r < 4; ++r)                               \
      red[wv][mt * 16 + quad * 4 + r][f * 16 + lnk] = acc[mt][f][r];          \
  __syncthreads();                                                            \
  _Pragma("unroll") for (int i = 0; i < 16; ++i) {                            \
    int idx = t + i * 256;                                                    \
    int m = idx >> 6;                                                         \
    int nc = idx & 63;                                                        \
    float s = red[0][m][nc] + red[1][m][nc] + red[2][m][nc] + red[3][m][nc];  \
    int n = nbase + nc;                                                       \
    float sc = scale[n];                                                      \
    (OUTPTR)[(size_t)m * N_DIM + n] =                                         \
        s * sc + sc * offset[n] * rowsum[m] + bias[n];                        \
  }

#define LOADW(CC, BUF)                                            \
  do {                                                            \
    _Pragma("unroll") for (int j = 0; j < 8; ++j) {               \
      const int* bj = W + (size_t)(k0 + (CC) * 32 + j) * N_DIM;   \
      _Pragma("unroll") for (int f = 0; f < 4; ++f)               \
          raw[BUF][f][j] = bj[laneoff[f]];                        \
    }                                                             \
  } while (0)

#define LOADA(CC, BUF)                                            \
  do {                                                            \
    const u16* ahc = xhp + (CC) * 2048;                           \
    const u16* alc = xlp + (CC) * 2048;                           \
    _Pragma("unroll") for (int mt = 0; mt < 4; ++mt) {            \
      abh[BUF][mt] = *(const bf16x8*)(ahc + mt * 128);            \
      abl[BUF][mt] = *(const bf16x8*)(alc + mt * 128);            \
    }                                                             \
  } while (0)

#define COMPUTE(CC, BUF)                                                     \
  do {                                                                       \
    bf16x8 bfr[4];                                                           \
    _Pragma("unroll") for (int f = 0; f < 4; ++f) {                          \
      union {                                                                \
        int i4[4];                                                           \
        bf16x8 v;                                                            \
      } u;                                                                   \
      _Pragma("unroll") for (int wd = 0; wd < 4; ++wd) {                     \
        unsigned lo = __float_as_uint((float)raw[BUF][f][2 * wd]);           \
        unsigned hi = __float_as_uint((float)raw[BUF][f][2 * wd + 1]);       \
        u.i4[wd] = (int)((lo >> 16) | (hi & 0xFFFF0000u)); /* exact */       \
      }                                                                      \
      bfr[f] = u.v;                                                          \
    }                                                                        \
    _Pragma("unroll") for (int mt = 0; mt < 4; ++mt) {                       \
      _Pragma("unroll") for (int f = 0; f < 4; ++f) {                        \
        acc[mt][f] = __builtin_amdgcn_mfma_f32_16x16x32_bf16(                \
            abh[BUF][mt], bfr[f], acc[mt][f], 0, 0, 0);                      \
        acc[mt][f] = __builtin_amdgcn_mfma_f32_16x16x32_bf16(                \
            abl[BUF][mt], bfr[f], acc[mt][f], 0, 0, 0);                      \
      }                                                                      \
    }                                                                        \
  } while (0)

// real pass (unchanged v5)
__global__ __launch_bounds__(256, 1) void wqmm(
    const int* __restrict__ W, const u16* __restrict__ xh,
    const u16* __restrict__ xl, const float* __restrict__ rowsum,
    const float* __restrict__ scale, const float* __restrict__ offset,
    const float* __restrict__ bias, float* __restrict__ out) {
  WQMM_BODY(1, out)
}

// probe: identical pipeline x3, >137us so it surfaces in rocprof top-5.
// dur_R9 - dur_R8 = 3 * wqmm_warm (independent timing cross-check).
__global__ __launch_bounds__(256, 1) void wqmm_probe(
    const int* __restrict__ W, const u16* __restrict__ xh,
    const u16* __restrict__ xl, const float* __restrict__ rowsum,
    const float* __restrict__ scale, const float* __restrict__ offset,
    const float* __restrict__ bias, float* __restrict__ pout) {
  WQMM_BODY(3, pout)
}

#undef LOADW
#undef LOADA
#undef COMPUTE

extern "C" void kernel_launch(void* const* d_in, const int* in_sizes, int n_in,
                              void* d_out, int out_size, void* d_ws,
                              size_t ws_size, hipStream_t stream) {
  const float* x = (const float*)d_in[0];
  const int* W = (const int*)d_in[1];
  const float* scale = (const float*)d_in[2];
  const float* offset = (const float*)d_in[3];
  const float* bias = (const float*)d_in[4];
  float* out = (float*)d_out;

  char* wsb = (char*)d_ws;
  u16* xh = (u16*)wsb;                          // 512 KB
  u16* xl = xh + (size_t)M_DIM * K_DIM;         // 512 KB
  float* rowsum = (float*)(xl + (size_t)M_DIM * K_DIM);
  float* probe_out = (float*)(wsb + (8u << 20));  // scratch, never read

  prep_split<<<128, 256, 0, stream>>>(x, xh, xl);
  rowsum_k<<<64, 256, 0, stream>>>(x, rowsum);
  wqmm<<<NBLKS, 256, 0, stream>>>(W, xh, xl, rowsum, scale, offset, bias, out);
  // instrumentation probe — REMOVE NEXT ROUND
  wqmm_probe<<<NBLKS, 256, 0, stream>>>(W, xh, xl, rowsum, scale, offset,
                                        bias, probe_out);
}

// Round 10
// 343.682 us; speedup vs baseline: 1.3336x; 1.3336x over previous
//
#include <hip/hip_runtime.h>
#include <hip/hip_bf16.h>

#define M_DIM 64
#define K_DIM 4096
#define N_DIM 14336
#define NBLKS 224       // one block per 64 n-cols
#define KW 1024         // k-range per wave (4 waves cover K=4096)
#define WCHUNKS 32      // 32-k chunks per wave

typedef __attribute__((ext_vector_type(8))) short bf16x8;
typedef __attribute__((ext_vector_type(4))) float f32x4;
typedef unsigned short u16;

// ---------------------------------------------------------------------------
// prep: split x (fp32) into bf16 hi/lo, stored in MFMA-A-fragment layout:
// elem idx = (k/8)*(64*8) + m*8 + (k%8). hi+lo double-bf16 gives ~16-bit
// effective mantissa vs the fp32 reference.
__global__ void prep_split(const float* __restrict__ x, u16* __restrict__ xh,
                           u16* __restrict__ xl) {
  int tg = blockIdx.x * blockDim.x + threadIdx.x;  // 0..32767
  int kb = tg & 511;
  int m = tg >> 9;
  const float* xp = x + m * K_DIM + kb * 8;
  u16 hs[8], ls[8];
#pragma unroll
  for (int j = 0; j < 8; ++j) {
    float v = xp[j];
    unsigned hv = __float_as_uint(v) & 0xFFFF0000u;  // bf16 truncate (exact)
    float r = v - __uint_as_float(hv);
    hs[j] = (u16)(hv >> 16);
    ls[j] = (u16)(__float_as_uint(r) >> 16);
  }
  int o = kb * (M_DIM * 8) + m * 8;
  *(uint4*)(xh + o) = *(uint4*)hs;
  *(uint4*)(xl + o) = *(uint4*)ls;
}

// rowsum(x) per row m (for the offset term: out += scale*offset*rowsum[m])
__global__ void rowsum_k(const float* __restrict__ x, float* __restrict__ rs) {
  int m = blockIdx.x;
  int t = threadIdx.x;
  float s = 0.f;
  for (int k = t; k < K_DIM; k += 256) s += x[m * K_DIM + k];
#pragma unroll
  for (int off = 32; off > 0; off >>= 1) s += __shfl_down(s, off, 64);
  __shared__ float red[4];
  if ((t & 63) == 0) red[t >> 6] = s;
  __syncthreads();
  if (t == 0) rs[m] = red[0] + red[1] + red[2] + red[3];
}

// ---------------------------------------------------------------------------
// Streaming GEMM v5 (final). Measured via R9 probe: 38.3 us/pass = ~100% of
// the 6.3 TB/s achievable HBM ceiling for the irreducible 241 MB stream
// (W 235 MB + out 3.7 MB + x ~2 MB). 224 blocks, one per 64 n-cols; block
// covers FULL K: wave wv owns k in [wv*1024, +1024) -> no inter-block
// k-reduction (no partials/atomics; R1-R7 showed those cost 10-100 us).
// W -> B-fragments directly as per-lane dwords (the f-loop's 4 loads cover a
// contiguous 256 B per quad row — fully coalesced); int->bf16 cvt in regs is
// exact (|w|<=128). A (x hi/lo) double-buffered from global (L2-hot, 1 MB).
// Intra-block k-reduction via LDS, fused affine epilogue, direct store.
__global__ __launch_bounds__(256, 1) void wqmm(
    const int* __restrict__ W, const u16* __restrict__ xh,
    const u16* __restrict__ xl, const float* __restrict__ rowsum,
    const float* __restrict__ scale, const float* __restrict__ offset,
    const float* __restrict__ bias, float* __restrict__ out) {
  __shared__ __align__(16) float red[4][64][66];  // 67.6 KB, pad 64->66

  const int t = threadIdx.x;
  const int lane = t & 63;
  const int wv = t >> 6;       // k-quarter
  const int quad = lane >> 4;
  const int lnk = lane & 15;
  const int nbase = blockIdx.x * 64;
  const int k0 = wv * KW;

  // loop-invariant per-lane dword offsets into W
  int laneoff[4];
#pragma unroll
  for (int f = 0; f < 4; ++f)
    laneoff[f] = quad * 8 * N_DIM + nbase + lnk + f * 16;

  const u16* xhp = xh + (size_t)(wv * 128 + quad) * 512 + lnk * 8;
  const u16* xlp = xl + (size_t)(wv * 128 + quad) * 512 + lnk * 8;

  f32x4 acc[4][4] = {};         // [m-tile][n-frag]
  int raw[2][4][8];             // W double buffer (literal indices only)
  bf16x8 abh[2][4], abl[2][4];  // A double buffer

#define LOADW(CC, BUF)                                            \
  do {                                                            \
    _Pragma("unroll") for (int j = 0; j < 8; ++j) {               \
      const int* bj = W + (size_t)(k0 + (CC) * 32 + j) * N_DIM;   \
      _Pragma("unroll") for (int f = 0; f < 4; ++f)               \
          raw[BUF][f][j] = bj[laneoff[f]];                        \
    }                                                             \
  } while (0)

#define LOADA(CC, BUF)                                            \
  do {                                                            \
    const u16* ahc = xhp + (CC) * 2048;                           \
    const u16* alc = xlp + (CC) * 2048;                           \
    _Pragma("unroll") for (int mt = 0; mt < 4; ++mt) {            \
      abh[BUF][mt] = *(const bf16x8*)(ahc + mt * 128);            \
      abl[BUF][mt] = *(const bf16x8*)(alc + mt * 128);            \
    }                                                             \
  } while (0)

#define COMPUTE(CC, BUF)                                                     \
  do {                                                                       \
    bf16x8 bfr[4];                                                           \
    _Pragma("unroll") for (int f = 0; f < 4; ++f) {                          \
      union {                                                                \
        int i4[4];                                                           \
        bf16x8 v;                                                            \
      } u;                                                                   \
      _Pragma("unroll") for (int wd = 0; wd < 4; ++wd) {                     \
        unsigned lo = __float_as_uint((float)raw[BUF][f][2 * wd]);           \
        unsigned hi = __float_as_uint((float)raw[BUF][f][2 * wd + 1]);       \
        u.i4[wd] = (int)((lo >> 16) | (hi & 0xFFFF0000u)); /* exact */       \
      }                                                                      \
      bfr[f] = u.v;                                                          \
    }                                                                        \
    _Pragma("unroll") for (int mt = 0; mt < 4; ++mt) {                       \
      _Pragma("unroll") for (int f = 0; f < 4; ++f) {                        \
        acc[mt][f] = __builtin_amdgcn_mfma_f32_16x16x32_bf16(                \
            abh[BUF][mt], bfr[f], acc[mt][f], 0, 0, 0);                      \
        acc[mt][f] = __builtin_amdgcn_mfma_f32_16x16x32_bf16(                \
            abl[BUF][mt], bfr[f], acc[mt][f], 0, 0, 0);                      \
      }                                                                      \
    }                                                                        \
  } while (0)

  LOADW(0, 0);
  LOADA(0, 0);
  for (int c = 0; c < WCHUNKS; c += 2) {  // literal buffer indices in body
    LOADW(c + 1, 1);
    LOADA(c + 1, 1);
    COMPUTE(c, 0);
    if (c + 2 < WCHUNKS) {
      LOADW(c + 2, 0);
      LOADA(c + 2, 0);
    }
    COMPUTE(c + 1, 1);
  }
#undef LOADW
#undef LOADA
#undef COMPUTE

  // intra-block k-reduction: each wave deposits its 64x64 tile
#pragma unroll
  for (int f = 0; f < 4; ++f)
#pragma unroll
    for (int mt = 0; mt < 4; ++mt)
#pragma unroll
      for (int r = 0; r < 4; ++r)
        red[wv][mt * 16 + quad * 4 + r][f * 16 + lnk] = acc[mt][f][r];
  __syncthreads();

  // fused epilogue: out = scale*sum + scale*offset*rowsum[m] + bias
#pragma unroll
  for (int i = 0; i < 16; ++i) {
    int idx = t + i * 256;  // linear over 64x64 tile -> coalesced stores
    int m = idx >> 6;
    int nc = idx & 63;
    float s = red[0][m][nc] + red[1][m][nc] + red[2][m][nc] + red[3][m][nc];
    int n = nbase + nc;
    float sc = scale[n];
    out[(size_t)m * N_DIM + n] = s * sc + sc * offset[n] * rowsum[m] + bias[n];
  }
}

extern "C" void kernel_launch(void* const* d_in, const int* in_sizes, int n_in,
                              void* d_out, int out_size, void* d_ws,
                              size_t ws_size, hipStream_t stream) {
  const float* x = (const float*)d_in[0];
  const int* W = (const int*)d_in[1];
  const float* scale = (const float*)d_in[2];
  const float* offset = (const float*)d_in[3];
  const float* bias = (const float*)d_in[4];
  float* out = (float*)d_out;

  char* wsb = (char*)d_ws;
  u16* xh = (u16*)wsb;                          // 512 KB
  u16* xl = xh + (size_t)M_DIM * K_DIM;         // 512 KB
  float* rowsum = (float*)(xl + (size_t)M_DIM * K_DIM);

  prep_split<<<128, 256, 0, stream>>>(x, xh, xl);
  rowsum_k<<<64, 256, 0, stream>>>(x, rowsum);
  wqmm<<<NBLKS, 256, 0, stream>>>(W, xh, xl, rowsum, scale, offset, bias, out);
}